// Round 4
// baseline (128.180 us; speedup 1.0000x reference)
//
#include <hip/hip_runtime.h>
#include <hip/hip_bf16.h>

// SimpleRetention: B=8, SEQ=2048, HIDDEN=512, HEAD=64, CHUNK=256, GAMMA=0.96875
// v4: proj restructured to single-shot K staging (1 staging barrier, 16
//     uninterrupted MFMA k-steps, max memory-level parallelism on the X read).
//     prep/attn unchanged from v3 (verified).

typedef __attribute__((ext_vector_type(8))) short short8;
typedef __attribute__((ext_vector_type(4))) float floatx4;

#define LOG2GAMMA (-0.04580350f)  // log2(0.96875)

static __device__ __forceinline__ unsigned short f2bf(float f) {
    __hip_bfloat16 h = __float2bfloat16(f);
    return *reinterpret_cast<unsigned short*>(&h);
}

// Fragment storage convention (per 16x16x32 MFMA load, 16 B per lane):
//   frag_slot = ((tile_k_index)*64 + lane)*8,  lane = quad*16 + l15
//   A-frag: l15 = row m, k = quad*8+j   |   B-frag: l15 = col n, k = quad*8+j

// ---------------------------------------------------------------------------
// Kernel 0: Wfrag (B-frag order, tiles 0..3=WQ 4..7=WK 8..11=WV) + xpos tables
// tabs: 4 tables of [2048][32] f32: 0=cosQ 1=sinQ 2=cosK 3=sinK
// ---------------------------------------------------------------------------
__global__ __launch_bounds__(256) void prep_kernel(
    const float* __restrict__ Wq, const float* __restrict__ Wk,
    const float* __restrict__ Wv,
    __hip_bfloat16* __restrict__ Wfrag, float* __restrict__ tabs)
{
    int idx = blockIdx.x * 256 + threadIdx.x;
    const int WF_N = 192 * 512;
    if (idx < WF_N) {
        int j    = idx & 7;
        int n15  = (idx >> 3) & 15;
        int quad = (idx >> 7) & 3;
        int kkg  = (idx >> 9) & 15;
        int tile = idx >> 13;              // 0..11
        int n = tile * 16 + n15;           // 0..191 (proj output channel)
        int k = kkg * 32 + quad * 8 + j;   // 0..511 (hidden)
        int m = n >> 6, c = n & 63;
        const float* W = (m == 0) ? Wq : ((m == 1) ? Wk : Wv);
        Wfrag[idx] = __float2bfloat16(W[k * 64 + c]);
    } else {
        int t2 = idx - WF_N;
        if (t2 < 4 * 2048 * 32) {
            int tab = t2 >> 16;          // 0..3
            int rem = t2 & 65535;
            int pos = rem >> 5;          // 0..2047
            int t   = rem & 31;          // 0..31
            float inv_freq = powf(10000.0f, -(float)t / 32.0f);
            float sinus = (float)pos * inv_freq;
            float s = sinf(sinus), c = cosf(sinus);
            float sv = (2.0f * (float)t + 0.4f * 64.0f) / (1.4f * 64.0f);
            float power = (float)pos / 512.0f;
            float scl = powf(sv, (tab >= 2) ? -power : power);
            tabs[t2] = ((tab & 1) == 0) ? c * scl : s * scl;
        }
    }
}

// ---------------------------------------------------------------------------
// Kernel 1: projections. 512 blocks x 32 rows, 4 waves (rh, nh).
// Single-shot staging: whole 32x512 X tile -> bf16 LDS (32.5 KB, pad 8),
// 16 coalesced float4 loads back-to-back (full MLP), ONE barrier, then all
// 16 MFMA k-steps. W B-frags stream coalesced from L2-resident Wfrag.
// LDS 33 KB -> 4 blocks/CU.
// ---------------------------------------------------------------------------
__global__ __launch_bounds__(256, 4) void proj_kernel(
    const float* __restrict__ X, const __hip_bfloat16* __restrict__ Wfrag,
    const float* __restrict__ tabs,
    __hip_bfloat16* __restrict__ Qfrag, __hip_bfloat16* __restrict__ Kfrag,
    __hip_bfloat16* __restrict__ Vfrag)
{
    __shared__ __hip_bfloat16 smem[32 * 520];  // 33280 B; main: lx[32][520]
    // epilogue reuse: bufQ = smem [32][72], bufK = +2304 [32][72],
    //                 bufV = +4608 [64][40] (transposed)

    int tid = threadIdx.x;
    int r0 = blockIdx.x * 32;               // global row base (b*2048 + n)
    int w = tid >> 6, lane = tid & 63, quad = lane >> 4, l15 = lane & 15;
    int rh = w & 1, nh = w >> 1;

    // ---- stage X tile 32x512 f32 -> bf16 LDS (16 float4/thread, coalesced)
#pragma unroll
    for (int u = 0; u < 16; u++) {
        int f = u * 256 + tid;
        int row = f >> 7, c = f & 127;
        float4 v = *(const float4*)(X + (r0 + row) * 512 + c * 4);
        ushort4 pk;
        pk.x = f2bf(v.x); pk.y = f2bf(v.y); pk.z = f2bf(v.z); pk.w = f2bf(v.w);
        *(ushort4*)&smem[row * 520 + c * 4] = pk;
    }
    __syncthreads();

    // ---- 16 uninterrupted MFMA k-steps
    floatx4 acc[6];
#pragma unroll
    for (int t = 0; t < 6; t++) acc[t] = (floatx4){0.f, 0.f, 0.f, 0.f};

#pragma unroll
    for (int ks = 0; ks < 16; ks++) {
        short8 a = *(const short8*)&smem[(rh * 16 + l15) * 520 + ks * 32 + quad * 8];
#pragma unroll
        for (int t = 0; t < 6; t++) {
            int tile = nh * 6 + t;
            short8 bfr = *(const short8*)(Wfrag + ((tile * 16 + ks) * 64 + lane) * 8);
            acc[t] = __builtin_amdgcn_mfma_f32_16x16x32_bf16(a, bfr, acc[t], 0, 0, 0);
        }
    }
    __syncthreads();   // lx reads done before epilogue overwrites smem

    // ---- epilogue. C/D layout: col = l15, row = quad*4+rg ----
    __hip_bfloat16* bufQ = smem;
    __hip_bfloat16* bufK = smem + 2304;
    __hip_bfloat16* bufV = smem + 4608;
    int b = r0 >> 11, n0 = r0 & 2047;
    int rrow = rh * 16 + quad * 4;

#pragma unroll
    for (int tl = 0; tl < 6; tl++) {
        int t = nh * 6 + tl;
#pragma unroll
        for (int rg = 0; rg < 4; rg++) {
            int row = rrow + rg;            // 0..31 within block
            int n = n0 + row;
            float val = acc[tl][rg];
            float prt = __shfl_xor(val, 1, 64);  // lane^1 == col^1, same row
            if (t < 4) {                    // Q, xpos upscale
                int ch = t * 16 + l15, tt = ch >> 1;
                float co = tabs[n * 32 + tt];
                float si = tabs[65536 + n * 32 + tt];
                float o = (l15 & 1) ? (val * co + prt * si) : (val * co - prt * si);
                bufQ[row * 72 + ch] = __float2bfloat16(o);
            } else if (t < 8) {             // K, xpos downscale
                int ch = (t - 4) * 16 + l15, tt = ch >> 1;
                float co = tabs[131072 + n * 32 + tt];
                float si = tabs[196608 + n * 32 + tt];
                float o = (l15 & 1) ? (val * co + prt * si) : (val * co - prt * si);
                bufK[row * 72 + ch] = __float2bfloat16(o);
            } else {                        // V, transposed [ch][row]
                int ch = (t - 8) * 16 + l15;
                bufV[ch * 40 + row] = __float2bfloat16(val);
            }
        }
    }
    __syncthreads();

    // cooperative frag-order stores (each thread: 16 B ds_read + uint4 store)
    {
        int tile2 = tid >> 7, kk = (tid >> 6) & 1, ln = tid & 63;
        int q2 = ln >> 4, m15 = ln & 15;
        size_t qkbase = ((((size_t)b * 128 + (n0 >> 4) + tile2) * 2 + kk) * 64 + ln) * 8;
        uint4 vq = *(const uint4*)&bufQ[(tile2 * 16 + m15) * 72 + kk * 32 + q2 * 8];
        *(uint4*)(Qfrag + qkbase) = vq;
        uint4 vk = *(const uint4*)&bufK[(tile2 * 16 + m15) * 72 + kk * 32 + q2 * 8];
        *(uint4*)(Kfrag + qkbase) = vk;
        int t2 = tid >> 6;                  // 0..3
        uint4 vv = *(const uint4*)&bufV[(t2 * 16 + m15) * 40 + q2 * 8];
        *(uint4*)(Vfrag + ((((size_t)b * 64 + (n0 >> 5)) * 4 + t2) * 64 + ln) * 8) = vv;
    }
}

// ---------------------------------------------------------------------------
// Kernel 2: banded retention, barrier-free hot loop (unchanged from v3).
// 512 blocks = (b, 32 q-rows). Waves (qh, h): q-half, chunk-half.
// KV chunks qc-3..qc (gamma^768 ~ 2.6e-11 << threshold).
// ---------------------------------------------------------------------------
__global__ __launch_bounds__(256, 3) void attn_kernel(
    const __hip_bfloat16* __restrict__ Qfrag, const __hip_bfloat16* __restrict__ Kfrag,
    const __hip_bfloat16* __restrict__ Vfrag, float* __restrict__ out)
{
    __shared__ __hip_bfloat16 lp[4][16 * 264];   // 33792 B, per-wave private

    int tid = threadIdx.x;
    int b = blockIdx.x >> 6, qt = blockIdx.x & 63;
    int q0 = qt * 32, qc = q0 >> 8;
    int w = tid >> 6, lane = tid & 63, quad = lane >> 4, l15 = lane & 15;
    int qh = w >> 1, h = w & 1;
    int qt16 = (q0 >> 4) + qh;

    short8 qf[2];
#pragma unroll
    for (int kk = 0; kk < 2; kk++)
        qf[kk] = *(const short8*)(Qfrag + ((((size_t)b * 128 + qt16) * 2 + kk) * 64 + lane) * 8);

    __hip_bfloat16* P = &lp[w][0];               // [16][264]

    floatx4 o[4];
#pragma unroll
    for (int t = 0; t < 4; t++) o[t] = (floatx4){0.f, 0.f, 0.f, 0.f};

    int kc0 = (qc >= 3) ? (qc - 3) : 0;
    for (int kc = kc0 + h; kc <= qc; kc += 2) {
        floatx4 s[16];
#pragma unroll
        for (int t = 0; t < 16; t++) s[t] = (floatx4){0.f, 0.f, 0.f, 0.f};
#pragma unroll
        for (int t = 0; t < 16; t++) {
#pragma unroll
            for (int kk = 0; kk < 2; kk++) {
                short8 bfr = *(const short8*)(Kfrag +
                    ((((size_t)b * 128 + kc * 16 + t) * 2 + kk) * 64 + lane) * 8);
                s[t] = __builtin_amdgcn_mfma_f32_16x16x32_bf16(qf[kk], bfr, s[t], 0, 0, 0);
            }
        }

        int i0 = q0 + qh * 16 + quad * 4;
        int kbase = kc * 256;
#pragma unroll
        for (int t = 0; t < 16; t++) {
            int j = kbase + t * 16 + l15;
#pragma unroll
            for (int rg = 0; rg < 4; rg++) {
                int d = i0 + rg - j; d = (d < 0) ? -d : d;
                float p = s[t][rg] * exp2f(LOG2GAMMA * (float)d);
                P[(quad * 4 + rg) * 264 + t * 16 + l15] = __float2bfloat16(p);
            }
        }

#pragma unroll
        for (int ks = 0; ks < 8; ks++) {
            short8 a = *(const short8*)&P[l15 * 264 + ks * 32 + quad * 8];
#pragma unroll
            for (int t2 = 0; t2 < 4; t2++) {
                short8 bfr = *(const short8*)(Vfrag +
                    ((((size_t)b * 64 + kc * 8 + ks) * 4 + t2) * 64 + lane) * 8);
                o[t2] = __builtin_amdgcn_mfma_f32_16x16x32_bf16(a, bfr, o[t2], 0, 0, 0);
            }
        }
    }

    // combine chunk halves: h==1 stashes o (f32) in its P region, h==0 adds
    float* mine = (float*)&lp[w][0];
    float* part = (float*)&lp[w ^ 1][0];
    if (h == 1) {
#pragma unroll
        for (int t2 = 0; t2 < 4; t2++)
#pragma unroll
            for (int rg = 0; rg < 4; rg++)
                mine[(quad * 4 + rg) * 64 + t2 * 16 + l15] = o[t2][rg];
    }
    __syncthreads();
    if (h == 0) {
        int rbase = b * 2048 + q0 + qh * 16 + quad * 4;
#pragma unroll
        for (int t2 = 0; t2 < 4; t2++)
#pragma unroll
            for (int rg = 0; rg < 4; rg++)
                out[(size_t)(rbase + rg) * 64 + t2 * 16 + l15] =
                    o[t2][rg] + part[(quad * 4 + rg) * 64 + t2 * 16 + l15];
    }
}

// ---------------------------------------------------------------------------
extern "C" void kernel_launch(void* const* d_in, const int* in_sizes, int n_in,
                              void* d_out, int out_size, void* d_ws, size_t ws_size,
                              hipStream_t stream) {
    const float* X  = (const float*)d_in[0];
    const float* Wq = (const float*)d_in[1];
    const float* Wk = (const float*)d_in[2];
    const float* Wv = (const float*)d_in[3];
    float* out = (float*)d_out;

    char* ws = (char*)d_ws;
    __hip_bfloat16* Wfrag = (__hip_bfloat16*)(ws);            // 196608 B
    float*          tabs  = (float*)(ws + 196608);            // 1048576 B
    __hip_bfloat16* Qfrag = (__hip_bfloat16*)(ws + 1245184);  // 2097152 B
    __hip_bfloat16* Kfrag = (__hip_bfloat16*)(ws + 3342336);  // 2097152 B
    __hip_bfloat16* Vfrag = (__hip_bfloat16*)(ws + 5439488);  // 2097152 B

    prep_kernel<<<1408, 256, 0, stream>>>(Wq, Wk, Wv, Wfrag, tabs);
    proj_kernel<<<512, 256, 0, stream>>>(X, Wfrag, tabs, Qfrag, Kfrag, Vfrag);
    attn_kernel<<<512, 256, 0, stream>>>(Qfrag, Kfrag, Vfrag, out);
}

// Round 6
// 111.783 us; speedup vs baseline: 1.1467x; 1.1467x over previous
//
#include <hip/hip_runtime.h>
#include <hip/hip_bf16.h>

// SimpleRetention: B=8, SEQ=2048, HIDDEN=512, HEAD=64, CHUNK=256, GAMMA=0.96875
// v6 = v5 with the attn grid fixed (1024 blocks, was 2048 -> OOB writes on
// d_out -> core dump). Chunked-retention form:
//   Off-diagonal chunks (all j<i): gamma^(i-j) = gamma^(il+1)*gamma^(255-jl)*gamma^(256m)
//   -> out += Qs @ (Z_{qc-1} + g256*Z_{qc-2} + g512*Z_{qc-3}), Z_c = Ks_c^T V_c.
//   Diagonal chunk keeps the per-element |i-j| decay + P round-trip path.

typedef __attribute__((ext_vector_type(8))) short short8;
typedef __attribute__((ext_vector_type(4))) float floatx4;

#define LOG2GAMMA (-0.04580350f)   // log2(0.96875)
#define GINV      (1.0f / 0.96875f)

static __device__ __forceinline__ unsigned short f2bf(float f) {
    __hip_bfloat16 h = __float2bfloat16(f);
    return *reinterpret_cast<unsigned short*>(&h);
}

// Fragment storage convention (per 16x16x32 MFMA operand, 16 B per lane):
//   slot = (frag_index*64 + lane)*8, lane = quad*16 + l15
//   A-frag: l15 = row m, k = quad*8+j   |   B-frag: l15 = col n, k = quad*8+j

// ---------------------------------------------------------------------------
// Kernel 0: Wfrag (B-frag order, tiles 0..3=WQ 4..7=WK 8..11=WV) + xpos tables
// tabs: 4 tables of [2048][32] f32: 0=cosQ 1=sinQ 2=cosK 3=sinK
// ---------------------------------------------------------------------------
__global__ __launch_bounds__(256) void prep_kernel(
    const float* __restrict__ Wq, const float* __restrict__ Wk,
    const float* __restrict__ Wv,
    __hip_bfloat16* __restrict__ Wfrag, float* __restrict__ tabs)
{
    int idx = blockIdx.x * 256 + threadIdx.x;
    const int WF_N = 192 * 512;
    if (idx < WF_N) {
        int j    = idx & 7;
        int n15  = (idx >> 3) & 15;
        int quad = (idx >> 7) & 3;
        int kkg  = (idx >> 9) & 15;
        int tile = idx >> 13;              // 0..11
        int n = tile * 16 + n15;           // 0..191 (proj output channel)
        int k = kkg * 32 + quad * 8 + j;   // 0..511 (hidden)
        int m = n >> 6, c = n & 63;
        const float* W = (m == 0) ? Wq : ((m == 1) ? Wk : Wv);
        Wfrag[idx] = __float2bfloat16(W[k * 64 + c]);
    } else {
        int t2 = idx - WF_N;
        if (t2 < 4 * 2048 * 32) {
            int tab = t2 >> 16;          // 0..3
            int rem = t2 & 65535;
            int pos = rem >> 5;          // 0..2047
            int t   = rem & 31;          // 0..31
            float inv_freq = powf(10000.0f, -(float)t / 32.0f);
            float sinus = (float)pos * inv_freq;
            float s = sinf(sinus), c = cosf(sinus);
            float sv = (2.0f * (float)t + 0.4f * 64.0f) / (1.4f * 64.0f);
            float power = (float)pos / 512.0f;
            float scl = powf(sv, (tab >= 2) ? -power : power);
            tabs[t2] = ((tab & 1) == 0) ? c * scl : s * scl;
        }
    }
}

// ---------------------------------------------------------------------------
// Kernel 1: projections + all fragment materialization.
// 512 blocks x 32 rows, 4 waves (rh, nh). Single-shot X staging (32x512 bf16,
// 33 KB LDS), one barrier, 16 MFMA k-steps streaming W B-frags from L2.
// Epilogue emits:  Qfrag (raw, A-layout)      Kfrag (raw, B-layout)
//                  Qsfrag (Q*g^(il+1), A)     Ktfrag (K^T*g^(255-jl), A-layout
//                  Vfrag (B-layout)            for the Z GEMM)
// ---------------------------------------------------------------------------
__global__ __launch_bounds__(256, 4) void proj_kernel(
    const float* __restrict__ X, const __hip_bfloat16* __restrict__ Wfrag,
    const float* __restrict__ tabs,
    __hip_bfloat16* __restrict__ Qfrag, __hip_bfloat16* __restrict__ Kfrag,
    __hip_bfloat16* __restrict__ Vfrag, __hip_bfloat16* __restrict__ Qsfrag,
    __hip_bfloat16* __restrict__ Ktfrag)
{
    __shared__ __hip_bfloat16 smem[32 * 520];  // 33280 B; main: lx[32][520]
    // epilogue reuse: bufQ=+0 [32][72], bufK=+2304 [32][72],
    //                 bufV=+4608 [64][40] (transposed), bufQs=+7168 [32][72]

    int tid = threadIdx.x;
    int r0 = blockIdx.x * 32;               // global row base (b*2048 + n)
    int w = tid >> 6, lane = tid & 63, quad = lane >> 4, l15 = lane & 15;
    int rh = w & 1, nh = w >> 1;

    // ---- stage X tile 32x512 f32 -> bf16 LDS (16 float4/thread, coalesced)
#pragma unroll
    for (int u = 0; u < 16; u++) {
        int f = u * 256 + tid;
        int row = f >> 7, c = f & 127;
        float4 v = *(const float4*)(X + (r0 + row) * 512 + c * 4);
        ushort4 pk;
        pk.x = f2bf(v.x); pk.y = f2bf(v.y); pk.z = f2bf(v.z); pk.w = f2bf(v.w);
        *(ushort4*)&smem[row * 520 + c * 4] = pk;
    }
    __syncthreads();

    floatx4 acc[6];
#pragma unroll
    for (int t = 0; t < 6; t++) acc[t] = (floatx4){0.f, 0.f, 0.f, 0.f};

#pragma unroll
    for (int ks = 0; ks < 16; ks++) {
        short8 a = *(const short8*)&smem[(rh * 16 + l15) * 520 + ks * 32 + quad * 8];
#pragma unroll
        for (int t = 0; t < 6; t++) {
            int tile = nh * 6 + t;
            short8 bfr = *(const short8*)(Wfrag + ((tile * 16 + ks) * 64 + lane) * 8);
            acc[t] = __builtin_amdgcn_mfma_f32_16x16x32_bf16(a, bfr, acc[t], 0, 0, 0);
        }
    }
    __syncthreads();   // lx reads done before epilogue overwrites smem

    // ---- epilogue. C/D layout: col = l15, row = quad*4+rg ----
    __hip_bfloat16* bufQ  = smem;
    __hip_bfloat16* bufK  = smem + 2304;
    __hip_bfloat16* bufV  = smem + 4608;
    __hip_bfloat16* bufQs = smem + 7168;
    int b = r0 >> 11, n0 = r0 & 2047;
    int rrow = rh * 16 + quad * 4;

#pragma unroll
    for (int tl = 0; tl < 6; tl++) {
        int t = nh * 6 + tl;
#pragma unroll
        for (int rg = 0; rg < 4; rg++) {
            int row = rrow + rg;            // 0..31 within block
            int n = n0 + row;
            float val = acc[tl][rg];
            float prt = __shfl_xor(val, 1, 64);  // lane^1 == col^1, same row
            if (t < 4) {                    // Q, xpos upscale
                int ch = t * 16 + l15, tt = ch >> 1;
                float co = tabs[n * 32 + tt];
                float si = tabs[65536 + n * 32 + tt];
                float o = (l15 & 1) ? (val * co + prt * si) : (val * co - prt * si);
                bufQ[row * 72 + ch] = __float2bfloat16(o);
                float qs = exp2f(LOG2GAMMA * (float)((n & 255) + 1));
                bufQs[row * 72 + ch] = __float2bfloat16(o * qs);
            } else if (t < 8) {             // K, xpos downscale
                int ch = (t - 4) * 16 + l15, tt = ch >> 1;
                float co = tabs[131072 + n * 32 + tt];
                float si = tabs[196608 + n * 32 + tt];
                float o = (l15 & 1) ? (val * co + prt * si) : (val * co - prt * si);
                bufK[row * 72 + ch] = __float2bfloat16(o);
            } else {                        // V, transposed [ch][row]
                int ch = (t - 8) * 16 + l15;
                bufV[ch * 40 + row] = __float2bfloat16(val);
            }
        }
    }
    __syncthreads();

    // ---- cooperative frag-order stores ----
    {
        int tile2 = tid >> 7, kk = (tid >> 6) & 1, ln = tid & 63;
        int q2 = ln >> 4, m15 = ln & 15;
        size_t qkbase = ((((size_t)b * 128 + (n0 >> 4) + tile2) * 2 + kk) * 64 + ln) * 8;
        uint4 vq = *(const uint4*)&bufQ[(tile2 * 16 + m15) * 72 + kk * 32 + q2 * 8];
        *(uint4*)(Qfrag + qkbase) = vq;
        uint4 vqs = *(const uint4*)&bufQs[(tile2 * 16 + m15) * 72 + kk * 32 + q2 * 8];
        *(uint4*)(Qsfrag + qkbase) = vqs;
        uint4 vk = *(const uint4*)&bufK[(tile2 * 16 + m15) * 72 + kk * 32 + q2 * 8];
        *(uint4*)(Kfrag + qkbase) = vk;
        int t2 = tid >> 6;                  // 0..3
        uint4 vv = *(const uint4*)&bufV[(t2 * 16 + m15) * 40 + q2 * 8];
        *(uint4*)(Vfrag + ((((size_t)b * 64 + (n0 >> 5)) * 4 + t2) * 64 + ln) * 8) = vv;
    }
    // ---- Ktfrag: A-layout of K^T scaled by gamma^(255-jl), for Z = Ks^T V ----
    {
        int wdt = tid >> 6, ln2 = tid & 63;          // wdt = d-tile 0..3
        int q2 = ln2 >> 4, m15 = ln2 & 15;           // m15 = d within tile
        int jb0 = (n0 & 255) + q2 * 8;               // base key (chunk-local)
        float sc = exp2f(LOG2GAMMA * (float)(255 - jb0));
        short8 pk;
#pragma unroll
        for (int jj = 0; jj < 8; jj++) {
            float v = __bfloat162float(bufK[(q2 * 8 + jj) * 72 + wdt * 16 + m15]) * sc;
            pk[jj] = (short)f2bf(v);
            sc *= GINV;
        }
        int c = n0 >> 8, ksg = (n0 >> 5) & 7;
        *(short8*)(Ktfrag + ((((size_t)(b * 8 + c) * 4 + wdt) * 8 + ksg) * 64 + ln2) * 8) = pk;
    }
}

// ---------------------------------------------------------------------------
// Kernel 2: Z_c = Ks_c^T V_c  (64 d x 64 v, K=256 keys) per (b, chunk).
// 64 blocks x 4 waves (wave = d-tile). Output re-laid to B-frag order (f32)
// via an LDS transpose so attn can consume it as the H operand.
// ---------------------------------------------------------------------------
__global__ __launch_bounds__(256, 2) void zk_kernel(
    const __hip_bfloat16* __restrict__ Ktfrag,
    const __hip_bfloat16* __restrict__ Vfrag, float* __restrict__ Zf)
{
    __shared__ float zz[64 * 68];   // 17408 B

    int tid = threadIdx.x;
    int b = blockIdx.x >> 3, c = blockIdx.x & 7;
    int w = tid >> 6, lane = tid & 63, quad = lane >> 4, l15 = lane & 15;

    floatx4 acc[4];
#pragma unroll
    for (int t = 0; t < 4; t++) acc[t] = (floatx4){0.f, 0.f, 0.f, 0.f};

#pragma unroll
    for (int ks = 0; ks < 8; ks++) {
        short8 a = *(const short8*)(Ktfrag +
            ((((size_t)(b * 8 + c) * 4 + w) * 8 + ks) * 64 + lane) * 8);
#pragma unroll
        for (int vt = 0; vt < 4; vt++) {
            short8 bfr = *(const short8*)(Vfrag +
                ((((size_t)b * 64 + c * 8 + ks) * 4 + vt) * 64 + lane) * 8);
            acc[vt] = __builtin_amdgcn_mfma_f32_16x16x32_bf16(a, bfr, acc[vt], 0, 0, 0);
        }
    }
    // C-layout (row d = w*16+quad*4+rg, col v = vt*16+l15) -> LDS
#pragma unroll
    for (int vt = 0; vt < 4; vt++)
#pragma unroll
        for (int rg = 0; rg < 4; rg++)
            zz[(w * 16 + quad * 4 + rg) * 68 + vt * 16 + l15] = acc[vt][rg];
    __syncthreads();

    // B-frag-order f32 store: thread = (vt, lane); 2 kk x 8 jd values
    {
        int vt = tid >> 6;
#pragma unroll
        for (int kk = 0; kk < 2; kk++) {
            float v[8];
#pragma unroll
            for (int jd = 0; jd < 8; jd++)
                v[jd] = zz[(kk * 32 + quad * 8 + jd) * 68 + vt * 16 + l15];
            float* zp = Zf + (((((size_t)(b * 8 + c) * 4 + vt) * 2 + kk) * 64 + lane) * 8);
            *(float4*)zp       = (float4){v[0], v[1], v[2], v[3]};
            *(float4*)(zp + 4) = (float4){v[4], v[5], v[6], v[7]};
        }
    }
}

// ---------------------------------------------------------------------------
// Kernel 3: per-q-tile retention. 1024 blocks = (b in [0,8), 128 q-tiles),
// 128 thr (2 waves). Wave h: diagonal-chunk keys h*128..+127 (QK + |i-j|
// decay + P round-trip + PV) and its kk=h half of the cross term Qs @ H,
// H = Z_{qc-1} + g256*Z_{qc-2} + g512*Z_{qc-3} (combined f32, one bf16
// rounding). One barrier total.
// ---------------------------------------------------------------------------
__global__ __launch_bounds__(128, 4) void attn_kernel(
    const __hip_bfloat16* __restrict__ Qfrag, const __hip_bfloat16* __restrict__ Kfrag,
    const __hip_bfloat16* __restrict__ Vfrag, const __hip_bfloat16* __restrict__ Qsfrag,
    const float* __restrict__ Zf, float* __restrict__ out)
{
    __shared__ __hip_bfloat16 P[2 * 16 * 132];   // 8448 B (stride 132: conflict-free)
    __shared__ float obuf[16 * 68];              // 4352 B

    int tid = threadIdx.x;
    int b = blockIdx.x >> 7, qt = blockIdx.x & 127;   // 1024 blocks: b in [0,8)
    int qc = qt >> 4;
    int h = tid >> 6, lane = tid & 63, quad = lane >> 4, l15 = lane & 15;
    __hip_bfloat16* Pw = P + h * 2112;

    short8 qf[2];
#pragma unroll
    for (int kk = 0; kk < 2; kk++)
        qf[kk] = *(const short8*)(Qfrag + (((size_t)(b * 128 + qt) * 2 + kk) * 64 + lane) * 8);

    floatx4 o[4];
#pragma unroll
    for (int t = 0; t < 4; t++) o[t] = (floatx4){0.f, 0.f, 0.f, 0.f};

    int il0 = (qt & 15) * 16 + quad * 4;         // chunk-local q row base

    // ---- diagonal chunk, this wave's 128 keys, 2 groups of 4 ktiles ----
#pragma unroll
    for (int g = 0; g < 2; g++) {
        floatx4 s[4];
#pragma unroll
        for (int t = 0; t < 4; t++) s[t] = (floatx4){0.f, 0.f, 0.f, 0.f};
#pragma unroll
        for (int t = 0; t < 4; t++) {
            int kt = qc * 16 + h * 8 + g * 4 + t;
#pragma unroll
            for (int kk = 0; kk < 2; kk++) {
                short8 bfr = *(const short8*)(Kfrag +
                    (((size_t)(b * 128 + kt) * 2 + kk) * 64 + lane) * 8);
                s[t] = __builtin_amdgcn_mfma_f32_16x16x32_bf16(qf[kk], bfr, s[t], 0, 0, 0);
            }
        }
#pragma unroll
        for (int t = 0; t < 4; t++) {
            int jl = h * 128 + (g * 4 + t) * 16 + l15;
#pragma unroll
            for (int rg = 0; rg < 4; rg++) {
                int d = il0 + rg - jl; d = (d < 0) ? -d : d;
                float p = s[t][rg] * exp2f(LOG2GAMMA * (float)d);
                Pw[(quad * 4 + rg) * 132 + (g * 4 + t) * 16 + l15] = __float2bfloat16(p);
            }
        }
    }
    // PV over this wave's 128 keys (in-wave DS ordering, no barrier)
#pragma unroll
    for (int ks = 0; ks < 4; ks++) {
        short8 a = *(const short8*)&Pw[l15 * 132 + ks * 32 + quad * 8];
#pragma unroll
        for (int vt = 0; vt < 4; vt++) {
            short8 bfr = *(const short8*)(Vfrag +
                ((((size_t)b * 64 + qc * 8 + h * 4 + ks) * 4 + vt) * 64 + lane) * 8);
            o[vt] = __builtin_amdgcn_mfma_f32_16x16x32_bf16(a, bfr, o[vt], 0, 0, 0);
        }
    }

    // ---- cross-chunk term: Qs @ H, kk = h half ----
    if (qc > 0) {
        short8 aq = *(const short8*)(Qsfrag +
            (((size_t)(b * 128 + qt) * 2 + h) * 64 + lane) * 8);
        int nz = (qc < 3) ? qc : 3;
        float cm0 = 1.0f;
        float cm1 = exp2f(LOG2GAMMA * 256.0f);
        float cm2 = exp2f(LOG2GAMMA * 512.0f);
#pragma unroll
        for (int vt = 0; vt < 4; vt++) {
            float hv[8];
#pragma unroll
            for (int jd = 0; jd < 8; jd++) hv[jd] = 0.f;
            for (int m = 0; m < nz; m++) {
                float cm = (m == 0) ? cm0 : ((m == 1) ? cm1 : cm2);
                const float* zp = Zf +
                    (((((size_t)(b * 8 + qc - 1 - m) * 4 + vt) * 2 + h) * 64 + lane) * 8);
                float4 z0 = *(const float4*)zp;
                float4 z1 = *(const float4*)(zp + 4);
                hv[0] += cm * z0.x; hv[1] += cm * z0.y;
                hv[2] += cm * z0.z; hv[3] += cm * z0.w;
                hv[4] += cm * z1.x; hv[5] += cm * z1.y;
                hv[6] += cm * z1.z; hv[7] += cm * z1.w;
            }
            short8 hb;
#pragma unroll
            for (int jd = 0; jd < 8; jd++) hb[jd] = (short)f2bf(hv[jd]);
            o[vt] = __builtin_amdgcn_mfma_f32_16x16x32_bf16(aq, hb, o[vt], 0, 0, 0);
        }
    }

    // ---- combine the two waves ----
    if (h == 1) {
#pragma unroll
        for (int vt = 0; vt < 4; vt++)
#pragma unroll
            for (int rg = 0; rg < 4; rg++)
                obuf[(quad * 4 + rg) * 68 + vt * 16 + l15] = o[vt][rg];
    }
    __syncthreads();
    if (h == 0) {
        int rbase = b * 2048 + qt * 16 + quad * 4;
#pragma unroll
        for (int vt = 0; vt < 4; vt++)
#pragma unroll
            for (int rg = 0; rg < 4; rg++)
                out[(size_t)(rbase + rg) * 64 + vt * 16 + l15] =
                    o[vt][rg] + obuf[(quad * 4 + rg) * 68 + vt * 16 + l15];
    }
}

// ---------------------------------------------------------------------------
extern "C" void kernel_launch(void* const* d_in, const int* in_sizes, int n_in,
                              void* d_out, int out_size, void* d_ws, size_t ws_size,
                              hipStream_t stream) {
    const float* X  = (const float*)d_in[0];
    const float* Wq = (const float*)d_in[1];
    const float* Wk = (const float*)d_in[2];
    const float* Wv = (const float*)d_in[3];
    float* out = (float*)d_out;

    char* ws = (char*)d_ws;
    __hip_bfloat16* Wfrag  = (__hip_bfloat16*)(ws);             // 196608 B
    float*          tabs   = (float*)(ws + 196608);             // 1048576 B
    __hip_bfloat16* Qfrag  = (__hip_bfloat16*)(ws + 1245184);   // 2097152 B
    __hip_bfloat16* Kfrag  = (__hip_bfloat16*)(ws + 3342336);   // 2097152 B
    __hip_bfloat16* Vfrag  = (__hip_bfloat16*)(ws + 5439488);   // 2097152 B
    __hip_bfloat16* Qsfrag = (__hip_bfloat16*)(ws + 7536640);   // 2097152 B
    __hip_bfloat16* Ktfrag = (__hip_bfloat16*)(ws + 9633792);   // 2097152 B
    float*          Zf     = (float*)(ws + 11730944);           // 1048576 B

    prep_kernel<<<1408, 256, 0, stream>>>(Wq, Wk, Wv, Wfrag, tabs);
    proj_kernel<<<512, 256, 0, stream>>>(X, Wfrag, tabs, Qfrag, Kfrag, Vfrag,
                                         Qsfrag, Ktfrag);
    zk_kernel<<<64, 256, 0, stream>>>(Ktfrag, Vfrag, Zf);
    attn_kernel<<<1024, 128, 0, stream>>>(Qfrag, Kfrag, Vfrag, Qsfrag, Zf, out);
}

// Round 7
// 111.479 us; speedup vs baseline: 1.1498x; 1.0027x over previous
//
#include <hip/hip_runtime.h>
#include <hip/hip_bf16.h>

// SimpleRetention: B=8, SEQ=2048, HIDDEN=512, HEAD=64, CHUNK=256, GAMMA=0.96875
// v7: chunked retention (v6) +
//   proj waves re-split by tile-triple x 32 rows -> Wfrag L2 traffic halved
//   Qsfrag eliminated (cross-term row scale applied post-MFMA in f32)
//   zk split over K-dim halves (128 blocks); attn sums partial Z's

typedef __attribute__((ext_vector_type(8))) short short8;
typedef __attribute__((ext_vector_type(4))) float floatx4;

#define LOG2GAMMA (-0.04580350f)   // log2(0.96875)
#define GINV      (1.0f / 0.96875f)

static __device__ __forceinline__ unsigned short f2bf(float f) {
    __hip_bfloat16 h = __float2bfloat16(f);
    return *reinterpret_cast<unsigned short*>(&h);
}

// Fragment storage convention (per 16x16x32 MFMA operand, 16 B per lane):
//   slot = (frag_index*64 + lane)*8, lane = quad*16 + l15
//   A-frag: l15 = row m, k = quad*8+j   |   B-frag: l15 = col n, k = quad*8+j

// ---------------------------------------------------------------------------
// Kernel 0: Wfrag (B-frag order, tiles 0..3=WQ 4..7=WK 8..11=WV) + xpos tables
// tabs: 4 tables of [2048][32] f32: 0=cosQ 1=sinQ 2=cosK 3=sinK
// ---------------------------------------------------------------------------
__global__ __launch_bounds__(256) void prep_kernel(
    const float* __restrict__ Wq, const float* __restrict__ Wk,
    const float* __restrict__ Wv,
    __hip_bfloat16* __restrict__ Wfrag, float* __restrict__ tabs)
{
    int idx = blockIdx.x * 256 + threadIdx.x;
    const int WF_N = 192 * 512;
    if (idx < WF_N) {
        int j    = idx & 7;
        int n15  = (idx >> 3) & 15;
        int quad = (idx >> 7) & 3;
        int kkg  = (idx >> 9) & 15;
        int tile = idx >> 13;              // 0..11
        int n = tile * 16 + n15;           // 0..191 (proj output channel)
        int k = kkg * 32 + quad * 8 + j;   // 0..511 (hidden)
        int m = n >> 6, c = n & 63;
        const float* W = (m == 0) ? Wq : ((m == 1) ? Wk : Wv);
        Wfrag[idx] = __float2bfloat16(W[k * 64 + c]);
    } else {
        int t2 = idx - WF_N;
        if (t2 < 4 * 2048 * 32) {
            int tab = t2 >> 16;          // 0..3
            int rem = t2 & 65535;
            int pos = rem >> 5;          // 0..2047
            int t   = rem & 31;          // 0..31
            float inv_freq = powf(10000.0f, -(float)t / 32.0f);
            float sinus = (float)pos * inv_freq;
            float s = sinf(sinus), c = cosf(sinus);
            float sv = (2.0f * (float)t + 0.4f * 64.0f) / (1.4f * 64.0f);
            float power = (float)pos / 512.0f;
            float scl = powf(sv, (tab >= 2) ? -power : power);
            tabs[t2] = ((tab & 1) == 0) ? c * scl : s * scl;
        }
    }
}

// ---------------------------------------------------------------------------
// Kernel 1: projections + fragment materialization.
// 512 blocks x 32 rows, 4 waves. Wave nh: tiles 3nh..3nh+2 x all 32 rows
// (2 A-frags, 3 B-loads per k-step -> half the Wfrag L2 traffic of v6).
// Single-shot X staging (32x512 bf16, 33 KB LDS), one barrier, 16 k-steps.
// Epilogue: Qfrag (A-layout), Kfrag (B), Vfrag (B), Ktfrag (A-layout K^T
// scaled by gamma^(255-jl) for the Z GEMM). No Qsfrag (scale post-MFMA).
// ---------------------------------------------------------------------------
__global__ __launch_bounds__(256, 4) void proj_kernel(
    const float* __restrict__ X, const __hip_bfloat16* __restrict__ Wfrag,
    const float* __restrict__ tabs,
    __hip_bfloat16* __restrict__ Qfrag, __hip_bfloat16* __restrict__ Kfrag,
    __hip_bfloat16* __restrict__ Vfrag, __hip_bfloat16* __restrict__ Ktfrag)
{
    __shared__ __hip_bfloat16 smem[32 * 520];  // 33280 B; main: lx[32][520]
    // epilogue reuse: bufQ=+0 [32][72], bufK=+2304 [32][72],
    //                 bufV=+4608 [64][40] (transposed)

    int tid = threadIdx.x;
    int r0 = blockIdx.x * 32;               // global row base (b*2048 + n)
    int nh = tid >> 6, lane = tid & 63, quad = lane >> 4, l15 = lane & 15;

    // ---- stage X tile 32x512 f32 -> bf16 LDS (16 float4/thread, coalesced)
#pragma unroll
    for (int u = 0; u < 16; u++) {
        int f = u * 256 + tid;
        int row = f >> 7, c = f & 127;
        float4 v = *(const float4*)(X + (r0 + row) * 512 + c * 4);
        ushort4 pk;
        pk.x = f2bf(v.x); pk.y = f2bf(v.y); pk.z = f2bf(v.z); pk.w = f2bf(v.w);
        *(ushort4*)&smem[row * 520 + c * 4] = pk;
    }
    __syncthreads();

    // acc[tl*2 + r]: tile 3nh+tl, row-half r
    floatx4 acc[6];
#pragma unroll
    for (int t = 0; t < 6; t++) acc[t] = (floatx4){0.f, 0.f, 0.f, 0.f};

#pragma unroll
    for (int ks = 0; ks < 16; ks++) {
        short8 a0 = *(const short8*)&smem[l15 * 520 + ks * 32 + quad * 8];
        short8 a1 = *(const short8*)&smem[(16 + l15) * 520 + ks * 32 + quad * 8];
#pragma unroll
        for (int tl = 0; tl < 3; tl++) {
            int tile = nh * 3 + tl;
            short8 bfr = *(const short8*)(Wfrag + ((tile * 16 + ks) * 64 + lane) * 8);
            acc[tl * 2 + 0] = __builtin_amdgcn_mfma_f32_16x16x32_bf16(a0, bfr, acc[tl * 2 + 0], 0, 0, 0);
            acc[tl * 2 + 1] = __builtin_amdgcn_mfma_f32_16x16x32_bf16(a1, bfr, acc[tl * 2 + 1], 0, 0, 0);
        }
    }
    __syncthreads();   // lx reads done before epilogue overwrites smem

    // ---- epilogue. C/D layout: col = l15, row = quad*4+rg (+16*r) ----
    __hip_bfloat16* bufQ = smem;
    __hip_bfloat16* bufK = smem + 2304;
    __hip_bfloat16* bufV = smem + 4608;
    int b = r0 >> 11, n0 = r0 & 2047;

#pragma unroll
    for (int tl = 0; tl < 3; tl++) {
        int t = nh * 3 + tl;
#pragma unroll
        for (int r = 0; r < 2; r++) {
#pragma unroll
            for (int rg = 0; rg < 4; rg++) {
                int row = r * 16 + quad * 4 + rg;    // 0..31 within block
                int n = n0 + row;
                float val = acc[tl * 2 + r][rg];
                float prt = __shfl_xor(val, 1, 64);  // lane^1 == col^1, same row
                if (t < 4) {                    // Q, xpos upscale
                    int ch = t * 16 + l15, tt = ch >> 1;
                    float co = tabs[n * 32 + tt];
                    float si = tabs[65536 + n * 32 + tt];
                    float o = (l15 & 1) ? (val * co + prt * si) : (val * co - prt * si);
                    bufQ[row * 72 + ch] = __float2bfloat16(o);
                } else if (t < 8) {             // K, xpos downscale
                    int ch = (t - 4) * 16 + l15, tt = ch >> 1;
                    float co = tabs[131072 + n * 32 + tt];
                    float si = tabs[196608 + n * 32 + tt];
                    float o = (l15 & 1) ? (val * co + prt * si) : (val * co - prt * si);
                    bufK[row * 72 + ch] = __float2bfloat16(o);
                } else {                        // V, transposed [ch][row]
                    int ch = (t - 8) * 16 + l15;
                    bufV[ch * 40 + row] = __float2bfloat16(val);
                }
            }
        }
    }
    __syncthreads();

    // ---- cooperative frag-order stores ----
    {
        int tile2 = tid >> 7, kk = (tid >> 6) & 1, ln = tid & 63;
        int q2 = ln >> 4, m15 = ln & 15;
        size_t qkbase = ((((size_t)b * 128 + (n0 >> 4) + tile2) * 2 + kk) * 64 + ln) * 8;
        uint4 vq = *(const uint4*)&bufQ[(tile2 * 16 + m15) * 72 + kk * 32 + q2 * 8];
        *(uint4*)(Qfrag + qkbase) = vq;
        uint4 vk = *(const uint4*)&bufK[(tile2 * 16 + m15) * 72 + kk * 32 + q2 * 8];
        *(uint4*)(Kfrag + qkbase) = vk;
        int t2 = tid >> 6;                  // 0..3
        uint4 vv = *(const uint4*)&bufV[(t2 * 16 + m15) * 40 + q2 * 8];
        *(uint4*)(Vfrag + ((((size_t)b * 64 + (n0 >> 5)) * 4 + t2) * 64 + ln) * 8) = vv;
    }
    // ---- Ktfrag: A-layout of K^T scaled by gamma^(255-jl), for Z = Ks^T V ----
    {
        int wdt = tid >> 6, ln2 = tid & 63;          // wdt = d-tile 0..3
        int q2 = ln2 >> 4, m15 = ln2 & 15;           // m15 = d within tile
        int jb0 = (n0 & 255) + q2 * 8;               // base key (chunk-local)
        float sc = exp2f(LOG2GAMMA * (float)(255 - jb0));
        short8 pk;
#pragma unroll
        for (int jj = 0; jj < 8; jj++) {
            float v = __bfloat162float(bufK[(q2 * 8 + jj) * 72 + wdt * 16 + m15]) * sc;
            pk[jj] = (short)f2bf(v);
            sc *= GINV;
        }
        int c = n0 >> 8, ksg = (n0 >> 5) & 7;
        *(short8*)(Ktfrag + ((((size_t)(b * 8 + c) * 4 + wdt) * 8 + ksg) * 64 + ln2) * 8) = pk;
    }
}

// ---------------------------------------------------------------------------
// Kernel 2: partial Z: Z[b][c][kh] = sum over keys kh*128..+127 of Ks^T V.
// 128 blocks = (b, c, kh), 4 waves (wave = d-tile). Output in B-frag order
// (f32) via LDS transpose; attn sums the two kh partials.
// ---------------------------------------------------------------------------
__global__ __launch_bounds__(256, 2) void zk_kernel(
    const __hip_bfloat16* __restrict__ Ktfrag,
    const __hip_bfloat16* __restrict__ Vfrag, float* __restrict__ Zf)
{
    __shared__ float zz[64 * 68];   // 17408 B

    int tid = threadIdx.x;
    int b = blockIdx.x >> 4, c = (blockIdx.x >> 1) & 7, kh = blockIdx.x & 1;
    int w = tid >> 6, lane = tid & 63, quad = lane >> 4, l15 = lane & 15;

    floatx4 acc[4];
#pragma unroll
    for (int t = 0; t < 4; t++) acc[t] = (floatx4){0.f, 0.f, 0.f, 0.f};

#pragma unroll
    for (int ks = 0; ks < 4; ks++) {
        int ksg = kh * 4 + ks;
        short8 a = *(const short8*)(Ktfrag +
            ((((size_t)(b * 8 + c) * 4 + w) * 8 + ksg) * 64 + lane) * 8);
#pragma unroll
        for (int vt = 0; vt < 4; vt++) {
            short8 bfr = *(const short8*)(Vfrag +
                ((((size_t)b * 64 + c * 8 + ksg) * 4 + vt) * 64 + lane) * 8);
            acc[vt] = __builtin_amdgcn_mfma_f32_16x16x32_bf16(a, bfr, acc[vt], 0, 0, 0);
        }
    }
    // C-layout (row d = w*16+quad*4+rg, col v = vt*16+l15) -> LDS
#pragma unroll
    for (int vt = 0; vt < 4; vt++)
#pragma unroll
        for (int rg = 0; rg < 4; rg++)
            zz[(w * 16 + quad * 4 + rg) * 68 + vt * 16 + l15] = acc[vt][rg];
    __syncthreads();

    // B-frag-order f32 store: thread = (vt, lane); 2 kk x 8 jd values
    {
        int vt = tid >> 6;
#pragma unroll
        for (int kk = 0; kk < 2; kk++) {
            float v[8];
#pragma unroll
            for (int jd = 0; jd < 8; jd++)
                v[jd] = zz[(kk * 32 + quad * 8 + jd) * 68 + vt * 16 + l15];
            float* zp = Zf +
                ((((((size_t)(b * 8 + c) * 2 + kh) * 4 + vt) * 2 + kk) * 64 + lane) * 8);
            *(float4*)zp       = (float4){v[0], v[1], v[2], v[3]};
            *(float4*)(zp + 4) = (float4){v[4], v[5], v[6], v[7]};
        }
    }
}

// ---------------------------------------------------------------------------
// Kernel 3: per-q-tile retention. 1024 blocks = (b, 128 q-tiles), 128 thr
// (2 waves). Wave h: diagonal-chunk keys h*128..+127 (QK + |i-j| decay + P
// round-trip + PV) and the kk=h half of the cross term Q @ H with post-MFMA
// row scaling by gamma^(il+1); H = sum_m g^(256m) * (Z[qc-1-m][0]+Z[..][1]).
// One barrier total.
// ---------------------------------------------------------------------------
__global__ __launch_bounds__(128, 4) void attn_kernel(
    const __hip_bfloat16* __restrict__ Qfrag, const __hip_bfloat16* __restrict__ Kfrag,
    const __hip_bfloat16* __restrict__ Vfrag, const float* __restrict__ Zf,
    float* __restrict__ out)
{
    __shared__ __hip_bfloat16 P[2 * 16 * 132];   // 8448 B (stride 132)
    __shared__ float obuf[16 * 68];              // 4352 B

    int tid = threadIdx.x;
    int b = blockIdx.x >> 7, qt = blockIdx.x & 127;
    int qc = qt >> 4;
    int h = tid >> 6, lane = tid & 63, quad = lane >> 4, l15 = lane & 15;
    __hip_bfloat16* Pw = P + h * 2112;

    short8 qf[2];
#pragma unroll
    for (int kk = 0; kk < 2; kk++)
        qf[kk] = *(const short8*)(Qfrag + (((size_t)(b * 128 + qt) * 2 + kk) * 64 + lane) * 8);

    floatx4 o[4];
#pragma unroll
    for (int t = 0; t < 4; t++) o[t] = (floatx4){0.f, 0.f, 0.f, 0.f};

    int il0 = (qt & 15) * 16 + quad * 4;         // chunk-local q row base

    // ---- diagonal chunk, this wave's 128 keys, 2 groups of 4 ktiles ----
#pragma unroll
    for (int g = 0; g < 2; g++) {
        floatx4 s[4];
#pragma unroll
        for (int t = 0; t < 4; t++) s[t] = (floatx4){0.f, 0.f, 0.f, 0.f};
#pragma unroll
        for (int t = 0; t < 4; t++) {
            int kt = qc * 16 + h * 8 + g * 4 + t;
#pragma unroll
            for (int kk = 0; kk < 2; kk++) {
                short8 bfr = *(const short8*)(Kfrag +
                    (((size_t)(b * 128 + kt) * 2 + kk) * 64 + lane) * 8);
                s[t] = __builtin_amdgcn_mfma_f32_16x16x32_bf16(qf[kk], bfr, s[t], 0, 0, 0);
            }
        }
#pragma unroll
        for (int t = 0; t < 4; t++) {
            int jl = h * 128 + (g * 4 + t) * 16 + l15;
#pragma unroll
            for (int rg = 0; rg < 4; rg++) {
                int d = il0 + rg - jl; d = (d < 0) ? -d : d;
                float p = s[t][rg] * exp2f(LOG2GAMMA * (float)d);
                Pw[(quad * 4 + rg) * 132 + (g * 4 + t) * 16 + l15] = __float2bfloat16(p);
            }
        }
    }
    // PV over this wave's 128 keys (in-wave DS ordering, no barrier)
#pragma unroll
    for (int ks = 0; ks < 4; ks++) {
        short8 a = *(const short8*)&Pw[l15 * 132 + ks * 32 + quad * 8];
#pragma unroll
        for (int vt = 0; vt < 4; vt++) {
            short8 bfr = *(const short8*)(Vfrag +
                ((((size_t)b * 64 + qc * 8 + h * 4 + ks) * 4 + vt) * 64 + lane) * 8);
            o[vt] = __builtin_amdgcn_mfma_f32_16x16x32_bf16(a, bfr, o[vt], 0, 0, 0);
        }
    }

    // ---- cross-chunk term: Q @ H into oc, post-scale by gamma^(il+1) ----
    if (qc > 0) {
        floatx4 oc[4];
#pragma unroll
        for (int t = 0; t < 4; t++) oc[t] = (floatx4){0.f, 0.f, 0.f, 0.f};
        int nz = (qc < 3) ? qc : 3;
        float cm1 = exp2f(LOG2GAMMA * 256.0f);
        float cm2 = exp2f(LOG2GAMMA * 512.0f);
#pragma unroll
        for (int vt = 0; vt < 4; vt++) {
            float hv[8];
#pragma unroll
            for (int jd = 0; jd < 8; jd++) hv[jd] = 0.f;
            for (int m = 0; m < nz; m++) {
                float cm = (m == 0) ? 1.0f : ((m == 1) ? cm1 : cm2);
#pragma unroll
                for (int kh = 0; kh < 2; kh++) {
                    const float* zp = Zf +
                        ((((((size_t)(b * 8 + qc - 1 - m) * 2 + kh) * 4 + vt) * 2 + h) * 64 + lane) * 8);
                    float4 z0 = *(const float4*)zp;
                    float4 z1 = *(const float4*)(zp + 4);
                    hv[0] += cm * z0.x; hv[1] += cm * z0.y;
                    hv[2] += cm * z0.z; hv[3] += cm * z0.w;
                    hv[4] += cm * z1.x; hv[5] += cm * z1.y;
                    hv[6] += cm * z1.z; hv[7] += cm * z1.w;
                }
            }
            short8 hb;
#pragma unroll
            for (int jd = 0; jd < 8; jd++) hb[jd] = (short)f2bf(hv[jd]);
            oc[vt] = __builtin_amdgcn_mfma_f32_16x16x32_bf16(qf[h], hb, oc[vt], 0, 0, 0);
        }
        float rs[4];
#pragma unroll
        for (int rg = 0; rg < 4; rg++)
            rs[rg] = exp2f(LOG2GAMMA * (float)(il0 + rg + 1));
#pragma unroll
        for (int vt = 0; vt < 4; vt++)
#pragma unroll
            for (int rg = 0; rg < 4; rg++)
                o[vt][rg] += oc[vt][rg] * rs[rg];
    }

    // ---- combine the two waves ----
    if (h == 1) {
#pragma unroll
        for (int vt = 0; vt < 4; vt++)
#pragma unroll
            for (int rg = 0; rg < 4; rg++)
                obuf[(quad * 4 + rg) * 68 + vt * 16 + l15] = o[vt][rg];
    }
    __syncthreads();
    if (h == 0) {
        int rbase = b * 2048 + qt * 16 + quad * 4;
#pragma unroll
        for (int vt = 0; vt < 4; vt++)
#pragma unroll
            for (int rg = 0; rg < 4; rg++)
                out[(size_t)(rbase + rg) * 64 + vt * 16 + l15] =
                    o[vt][rg] + obuf[(quad * 4 + rg) * 68 + vt * 16 + l15];
    }
}

// ---------------------------------------------------------------------------
extern "C" void kernel_launch(void* const* d_in, const int* in_sizes, int n_in,
                              void* d_out, int out_size, void* d_ws, size_t ws_size,
                              hipStream_t stream) {
    const float* X  = (const float*)d_in[0];
    const float* Wq = (const float*)d_in[1];
    const float* Wk = (const float*)d_in[2];
    const float* Wv = (const float*)d_in[3];
    float* out = (float*)d_out;

    char* ws = (char*)d_ws;
    __hip_bfloat16* Wfrag  = (__hip_bfloat16*)(ws);             // 196608 B
    float*          tabs   = (float*)(ws + 196608);             // 1048576 B
    __hip_bfloat16* Qfrag  = (__hip_bfloat16*)(ws + 1245184);   // 2097152 B
    __hip_bfloat16* Kfrag  = (__hip_bfloat16*)(ws + 3342336);   // 2097152 B
    __hip_bfloat16* Vfrag  = (__hip_bfloat16*)(ws + 5439488);   // 2097152 B
    __hip_bfloat16* Ktfrag = (__hip_bfloat16*)(ws + 7536640);   // 2097152 B
    float*          Zf     = (float*)(ws + 9633792);            // 2097152 B

    prep_kernel<<<1408, 256, 0, stream>>>(Wq, Wk, Wv, Wfrag, tabs);
    proj_kernel<<<512, 256, 0, stream>>>(X, Wfrag, tabs, Qfrag, Kfrag, Vfrag, Ktfrag);
    zk_kernel<<<128, 256, 0, stream>>>(Ktfrag, Vfrag, Zf);
    attn_kernel<<<1024, 128, 0, stream>>>(Qfrag, Kfrag, Vfrag, Zf, out);
}